// Round 4
// baseline (1452.581 us; speedup 1.0000x reference)
//
#include <hip/hip_runtime.h>
#include <hip/hip_bf16.h>
#include <cstdint>
#include <cstddef>

// MultiGateMixExperts: barrier-free fragment-streaming fp16 MFMA GEMMs.
// Frag-major layout: frag(tile16 t, kchunk32 c) = 1KB at ((t*32+c)*64+lane)*16B;
// lane l holds M[row=t*16+(l&15)][k=c*32+(l>>4)*8 .. +7] (fp16).
// R4: wave tile 128x64 (block 256x128, 2x2 waves) -> vector-load bytes/MAC
// drops 0.125 -> 0.046 (incl. cross-wave duplicate loads); TA/L1 ~60 B/cyc/CU
// ceiling moves from 27% to ~74% MfmaUtil. Register-double-buffered K-loop,
// no LDS staging, no __syncthreads in the K-loop.
// h1 = sigmoid(x@W1[e]+b1); h2 = relu(h1@W2[e]+b2);
// f = (h2@W2[e]+b2).Wo[e] fused into stage-3 epilogue (atomicAdd over n-blocks)
// out_i = softmax(x@Wg_i+bg_i) . (f+bo)

using half8   = __attribute__((ext_vector_type(8))) _Float16;
using floatx4 = __attribute__((ext_vector_type(4))) float;

// ---------------------------------------------------------------- GEMM ------
// ACT: 0=sigmoid, 1=relu (writes C in frag layout), 2=f-fused (no C store).
// Block 256x128, 4 waves, wave tile 128x64 (8x4 of 16x16x32).
// XCD-aware remap: flat%8 = XCD; one expert x contiguous M-stripe per XCD.
template<int ACT>
__global__ __launch_bounds__(256, 2)
void gemm_kernel(const _Float16* __restrict__ A, const _Float16* __restrict__ Bt,
                 const float* __restrict__ bias, _Float16* __restrict__ C,
                 size_t a_estride,
                 const float* __restrict__ Wo, float* __restrict__ f, int e0)
{
    __shared__ _Float16 lt[4][64 * 72];   // per-wave epilogue repack tile

    const int tid  = threadIdx.x;
    const int lane = tid & 63;
    const int w    = tid >> 6;      // wave 0..3
    const int wm   = w & 1;         // m half (128 rows)
    const int wn   = w >> 1;        // n half (64 cols)

    // --- XCD-aware remap (gridDim = {8, 32, g}) ---
    const int g    = gridDim.z;
    const int flat = blockIdx.x + (blockIdx.y << 3) + (blockIdx.z << 8);
    const int xcd  = flat & 7;
    int s = flat >> 3;
    int le, mb, nb;
    if (g <= 8) {
        const int p = 8 / g;            // XCDs per expert
        le = xcd / p;
        const int stripe = xcd % p;
        nb = s & 7;
        mb = stripe * (32 / p) + (s >> 3);
    } else {                            // g == 16
        le = (xcd << 1) | (s >> 8);
        s &= 255;
        nb = s & 7;
        mb = s >> 3;
    }
    const int m0 = mb * 256;
    const int n0 = nb * 128;

    const _Float16* Ae = A   + (size_t)le * a_estride;
    const _Float16* Be = Bt  + (size_t)le * (1024ull * 1024ull);
    const float*    be = bias + (size_t)le * 1024ull;
    _Float16*       Ce = C   + (size_t)le * (8192ull * 1024ull);

    const int mtb = (m0 >> 4) + wm * 8;   // wave's first m-tile (8 tiles)
    const int ntb = (n0 >> 4) + wn * 4;   // wave's first n-tile (4 tiles)

    // uniform bases (advance by 512 halves per k-chunk); constant VGPR offsets
    const _Float16* bA = Ae + (size_t)mtb * 32 * 512;
    const _Float16* bB = Be + (size_t)ntb * 32 * 512;
    uint32_t offA[8], offB[4];
#pragma unroll
    for (int i = 0; i < 8; ++i) offA[i] = (uint32_t)(i * 32 * 512 + lane * 8);
#pragma unroll
    for (int j = 0; j < 4; ++j) offB[j] = (uint32_t)(j * 32 * 512 + lane * 8);

    floatx4 acc[8][4];
#pragma unroll
    for (int i = 0; i < 8; ++i)
#pragma unroll
        for (int j = 0; j < 4; ++j) { floatx4 z = {0.f, 0.f, 0.f, 0.f}; acc[i][j] = z; }

    half8 a0[8], b0[4], a1[8], b1[4];
#pragma unroll
    for (int i = 0; i < 8; ++i) a0[i] = *(const half8*)(bA + offA[i]);
#pragma unroll
    for (int j = 0; j < 4; ++j) b0[j] = *(const half8*)(bB + offB[j]);
    bA += 512; bB += 512;

    for (int t = 0; t < 15; ++t) {
#pragma unroll
        for (int i = 0; i < 8; ++i) a1[i] = *(const half8*)(bA + offA[i]);
#pragma unroll
        for (int j = 0; j < 4; ++j) b1[j] = *(const half8*)(bB + offB[j]);
        bA += 512; bB += 512;
#pragma unroll
        for (int i = 0; i < 8; ++i)
#pragma unroll
            for (int j = 0; j < 4; ++j)
                acc[i][j] = __builtin_amdgcn_mfma_f32_16x16x32_f16(a0[i], b0[j], acc[i][j], 0, 0, 0);
#pragma unroll
        for (int i = 0; i < 8; ++i) a0[i] = *(const half8*)(bA + offA[i]);
#pragma unroll
        for (int j = 0; j < 4; ++j) b0[j] = *(const half8*)(bB + offB[j]);
        bA += 512; bB += 512;
#pragma unroll
        for (int i = 0; i < 8; ++i)
#pragma unroll
            for (int j = 0; j < 4; ++j)
                acc[i][j] = __builtin_amdgcn_mfma_f32_16x16x32_f16(a1[i], b1[j], acc[i][j], 0, 0, 0);
    }
#pragma unroll
    for (int i = 0; i < 8; ++i) a1[i] = *(const half8*)(bA + offA[i]);
#pragma unroll
    for (int j = 0; j < 4; ++j) b1[j] = *(const half8*)(bB + offB[j]);
#pragma unroll
    for (int i = 0; i < 8; ++i)
#pragma unroll
        for (int j = 0; j < 4; ++j)
            acc[i][j] = __builtin_amdgcn_mfma_f32_16x16x32_f16(a0[i], b0[j], acc[i][j], 0, 0, 0);
#pragma unroll
    for (int i = 0; i < 8; ++i)
#pragma unroll
        for (int j = 0; j < 4; ++j)
            acc[i][j] = __builtin_amdgcn_mfma_f32_16x16x32_f16(a1[i], b1[j], acc[i][j], 0, 0, 0);

    // ----- epilogue; C/D layout: col=lane&15, row=(lane>>4)*4+r -----
    const int q   = lane >> 4;
    const int l15 = lane & 15;
    float bj[4];
#pragma unroll
    for (int j = 0; j < 4; ++j) bj[j] = be[n0 + wn * 64 + j * 16 + l15];

    if (ACT == 2) {
        // f[m, e0+le] += sum_n (acc + b2[n]) * Wo[e0+le, n]
        const float* we = Wo + (size_t)(e0 + le) * 1024;
        float wj[4];
#pragma unroll
        for (int j = 0; j < 4; ++j) wj[j] = we[n0 + wn * 64 + j * 16 + l15];
#pragma unroll
        for (int i = 0; i < 8; ++i) {
            const int mbase = m0 + wm * 128 + i * 16 + q * 4;
#pragma unroll
            for (int r = 0; r < 4; ++r) {
                float sacc = 0.f;
#pragma unroll
                for (int j = 0; j < 4; ++j) sacc += (acc[i][j][r] + bj[j]) * wj[j];
#pragma unroll
                for (int m = 1; m < 16; m <<= 1) sacc += __shfl_xor(sacc, m, 64);
                if (l15 == 0) atomicAdd(&f[(size_t)(mbase + r) * 16 + (e0 + le)], sacc);
            }
        }
    } else {
        // per-wave LDS repack, 2 passes of 64 rows (no cross-wave -> no barrier)
        _Float16* T = lt[w];
        const int kcg0 = ((n0 + wn * 64) >> 5);
#pragma unroll
        for (int p = 0; p < 2; ++p) {
#pragma unroll
            for (int ii = 0; ii < 4; ++ii) {
                const int i = p * 4 + ii;
#pragma unroll
                for (int r = 0; r < 4; ++r) {
                    const int row = ii * 16 + q * 4 + r;
#pragma unroll
                    for (int j = 0; j < 4; ++j) {
                        float v = acc[i][j][r] + bj[j];
                        if (ACT == 0) v = 1.0f / (1.0f + __expf(-v));
                        else          v = fmaxf(v, 0.0f);
                        T[row * 72 + j * 16 + l15] = (_Float16)v;
                    }
                }
            }
#pragma unroll
            for (int ii = 0; ii < 4; ++ii) {
                const int mt = mtb + p * 4 + ii;
#pragma unroll
                for (int kci = 0; kci < 2; ++kci) {
                    half8 v = *(const half8*)(T + (ii * 16 + l15) * 72 + kci * 32 + q * 8);
                    *(half8*)(Ce + ((size_t)mt * 32 + kcg0 + kci) * 512 + lane * 8) = v;
                }
            }
        }
    }
}

// --------------------------------------- cast x to fp16 frag layout ---------
__global__ __launch_bounds__(256)
void castx_kernel(const float* __restrict__ x, _Float16* __restrict__ xb)
{
    __shared__ _Float16 tile[64 * 72];   // [m-local][k-local]
    const int k0 = blockIdx.x * 64;
    const int m0 = blockIdx.y * 64;
    const int tid = threadIdx.x;
    const int col4 = (tid & 15) * 4;
    const int rb   = tid >> 4;           // 0..15
#pragma unroll
    for (int p = 0; p < 4; ++p) {
        const int row = rb + p * 16;
        float4 a = *(const float4*)(x + (size_t)(m0 + row) * 1024 + k0 + col4);
        _Float16* d = tile + row * 72 + col4;
        d[0] = (_Float16)a.x; d[1] = (_Float16)a.y; d[2] = (_Float16)a.z; d[3] = (_Float16)a.w;
    }
    __syncthreads();
    const int lane = tid & 63, w = tid >> 6;
    const int l15 = lane & 15, q = lane >> 4;
#pragma unroll
    for (int ff = 0; ff < 2; ++ff) {
        const int fidx = w * 2 + ff;
        const int mi = fidx >> 1, kci = fidx & 1;
        half8 v = *(const half8*)(tile + (mi * 16 + l15) * 72 + kci * 32 + q * 8);
        const size_t mt = (m0 >> 4) + mi, kc = (k0 >> 5) + kci;
        *(half8*)(xb + (mt * 32 + kc) * 512 + lane * 8) = v;
    }
}

// ------------------- W1/W2 [d][h] fp32 -> frag-major fp16 (n=h, k=d) --------
__global__ __launch_bounds__(256)
void wtr_kernel(const float* __restrict__ W1, const float* __restrict__ W2,
                _Float16* __restrict__ W1F, _Float16* __restrict__ W2F)
{
    __shared__ _Float16 tile[64 * 73];   // [k-local][n-local], pad 73
    const int z = blockIdx.z;
    const float* src = (z < 16) ? (W1 + (size_t)z * 1048576ull) : (W2 + (size_t)(z - 16) * 1048576ull);
    _Float16*    dst = (z < 16) ? (W1F + (size_t)z * 1048576ull) : (W2F + (size_t)(z - 16) * 1048576ull);
    const int n0 = blockIdx.x * 64;
    const int k0 = blockIdx.y * 64;
    const int tid = threadIdx.x;
    const int col = tid & 63;
    const int rb  = tid >> 6;            // 0..3
#pragma unroll
    for (int p = 0; p < 16; ++p) {
        const int row = rb * 16 + p;
        tile[row * 73 + col] = (_Float16)src[(size_t)(k0 + row) * 1024 + n0 + col];
    }
    __syncthreads();
    const int lane = tid & 63, w = tid >> 6;
    const int l15 = lane & 15, q = lane >> 4;
#pragma unroll
    for (int ff = 0; ff < 2; ++ff) {
        const int fidx = w * 2 + ff;
        const int nti = fidx >> 1, kci = fidx & 1;
        half8 v;
#pragma unroll
        for (int jj = 0; jj < 8; ++jj)
            v[jj] = tile[(kci * 32 + q * 8 + jj) * 73 + nti * 16 + l15];
        const size_t nt = (n0 >> 4) + nti, kc = (k0 >> 5) + kci;
        *(half8*)(dst + (nt * 32 + kc) * 512 + lane * 8) = v;
    }
}

// ---------------------------------------------------- zero f ----------------
__global__ __launch_bounds__(256)
void zerof_kernel(float* __restrict__ f)
{
    const size_t i = ((size_t)blockIdx.x * 256 + threadIdx.x) * 4;
    float4 z = {0.f, 0.f, 0.f, 0.f};
    *(float4*)(f + i) = z;
}

// ------------------ gates (fp32, full precision) + softmax + combine --------
__global__ __launch_bounds__(256)
void final_kernel(const float* __restrict__ x,
                  const float* __restrict__ Wg1, const float* __restrict__ bg1,
                  const float* __restrict__ Wg2, const float* __restrict__ bg2,
                  const float* __restrict__ f, const float* __restrict__ bo,
                  float* __restrict__ out)
{
    const int lane = threadIdx.x & 63;
    const int w    = threadIdx.x >> 6;
    const int b    = blockIdx.x * 4 + w;
    const float* xr = x + (size_t)b * 1024;
    float gp1[16], gp2[16];
#pragma unroll
    for (int e = 0; e < 16; ++e) { gp1[e] = 0.f; gp2[e] = 0.f; }
    for (int t = 0; t < 16; ++t) {
        const int d = t * 64 + lane;
        const float xv = xr[d];
        const float* w1r = Wg1 + (size_t)d * 16;
        const float* w2r = Wg2 + (size_t)d * 16;
#pragma unroll
        for (int e = 0; e < 16; ++e) { gp1[e] += xv * w1r[e]; gp2[e] += xv * w2r[e]; }
    }
#pragma unroll
    for (int e = 0; e < 16; ++e) {
#pragma unroll
        for (int m = 1; m < 64; m <<= 1) {
            gp1[e] += __shfl_xor(gp1[e], m, 64);
            gp2[e] += __shfl_xor(gp2[e], m, 64);
        }
    }
    float a1[16], a2[16], m1 = -1e30f, m2 = -1e30f;
#pragma unroll
    for (int e = 0; e < 16; ++e) {
        a1[e] = gp1[e] + bg1[e]; m1 = fmaxf(m1, a1[e]);
        a2[e] = gp2[e] + bg2[e]; m2 = fmaxf(m2, a2[e]);
    }
    float s1 = 0.f, s2 = 0.f;
#pragma unroll
    for (int e = 0; e < 16; ++e) {
        a1[e] = __expf(a1[e] - m1); s1 += a1[e];
        a2[e] = __expf(a2[e] - m2); s2 += a2[e];
    }
    float o1 = 0.f, o2 = 0.f;
    const float* fb = f + (size_t)b * 16;
#pragma unroll
    for (int e = 0; e < 16; ++e) {
        const float fe = fb[e] + bo[e];
        o1 += a1[e] * fe; o2 += a2[e] * fe;
    }
    if (lane == 0) { out[b] = o1 / s1; out[8192 + b] = o2 / s2; }
}

// ----------------------------------------------------------------------------
extern "C" void kernel_launch(void* const* d_in, const int* in_sizes, int n_in,
                              void* d_out, int out_size, void* d_ws, size_t ws_size,
                              hipStream_t stream)
{
    const float* x   = (const float*)d_in[0];
    const float* W1  = (const float*)d_in[1];
    const float* b1  = (const float*)d_in[2];
    const float* W2  = (const float*)d_in[3];
    const float* b2  = (const float*)d_in[4];
    const float* Wo  = (const float*)d_in[5];
    const float* bo  = (const float*)d_in[6];
    const float* Wg1 = (const float*)d_in[7];
    const float* bg1 = (const float*)d_in[8];
    const float* Wg2 = (const float*)d_in[9];
    const float* bg2 = (const float*)d_in[10];
    float* out = (float*)d_out;

    char* ws = (char*)d_ws;
    _Float16* xb  = (_Float16*)(ws);                         // 16 MB (frag)
    _Float16* W1F = (_Float16*)(ws + 16777216ull);           // 32 MB (frag)
    _Float16* W2F = (_Float16*)(ws + 50331648ull);           // 32 MB (frag)
    float*    f   = (float*)   (ws + 83886080ull);           // 0.5 MB
    char* hbase = ws + 84410368ull;

    int g = 1;
    const int cands[4] = {16, 8, 4, 2};
    for (int ci = 0; ci < 4; ++ci) {
        const size_t need = 84410368ull + 2ull * cands[ci] * 16777216ull;
        if (need <= ws_size) { g = cands[ci]; break; }
    }
    _Float16* h0 = (_Float16*)hbase;
    _Float16* h1 = (_Float16*)(hbase + (size_t)g * 16777216ull);

    castx_kernel<<<dim3(16, 128), 256, 0, stream>>>(x, xb);
    wtr_kernel<<<dim3(16, 16, 32), 256, 0, stream>>>(W1, W2, W1F, W2F);
    zerof_kernel<<<128, 256, 0, stream>>>(f);

    for (int e0 = 0; e0 < 16; e0 += g) {
        gemm_kernel<0><<<dim3(8, 32, g), 256, 0, stream>>>(
            xb, W1F + (size_t)e0 * 1048576ull, b1 + (size_t)e0 * 1024, h0, 0,
            nullptr, nullptr, 0);
        gemm_kernel<1><<<dim3(8, 32, g), 256, 0, stream>>>(
            h0, W2F + (size_t)e0 * 1048576ull, b2 + (size_t)e0 * 1024, h1, 8192ull * 1024ull,
            nullptr, nullptr, 0);
        gemm_kernel<2><<<dim3(8, 32, g), 256, 0, stream>>>(
            h1, W2F + (size_t)e0 * 1048576ull, b2 + (size_t)e0 * 1024, h0, 8192ull * 1024ull,
            Wo, f, e0);
    }
    final_kernel<<<2048, 256, 0, stream>>>(x, Wg1, bg1, Wg2, bg2, f, bo, out);
}

// Round 5
// 1313.252 us; speedup vs baseline: 1.1061x; 1.1061x over previous
//
#include <hip/hip_runtime.h>
#include <hip/hip_bf16.h>
#include <cstdint>
#include <cstddef>

// MultiGateMixExperts: barrier-free fragment-streaming fp16 MFMA GEMMs.
// Frag-major layout: frag(tile16 t, kchunk32 c) = 1KB at ((t*32+c)*64+lane)*16B;
// lane l holds M[row=t*16+(l&15)][k=c*32+(l>>4)*8 .. +7] (fp16).
// R5: R3 tile (64x64 wave, 128x128 block, depth-2 reg prefetch) + mb-WINDOWED
// XCD remap: per XCD, iterate windows of 4 m-tiles (A-window 1MB) x all 8
// n-blocks -> per-XCD L2 set ~= A 1MB + B 2MB + streaming writes ~= 4MB L2.
// A re-reads become L2 hits (~200cyc) instead of L3 (~500-900cyc), which
// depth-2 prefetch + 3 waves/SIMD can cover.
// h1 = sigmoid(x@W1[e]+b1); h2 = relu(h1@W2[e]+b2);
// f = (h2@W2[e]+b2).Wo[e] fused into stage-3 epilogue (atomicAdd over n-blocks)
// out_i = softmax(x@Wg_i+bg_i) . (f+bo)

using half8   = __attribute__((ext_vector_type(8))) _Float16;
using floatx4 = __attribute__((ext_vector_type(4))) float;

// ---------------------------------------------------------------- GEMM ------
// ACT: 0=sigmoid, 1=relu (writes C in frag layout), 2=f-fused (no C store).
// Block 128x128, 4 waves (2x2), wave tile 64x64 (4x4 of 16x16x32).
template<int ACT>
__global__ __launch_bounds__(256, 2)
void gemm_kernel(const _Float16* __restrict__ A, const _Float16* __restrict__ Bt,
                 const float* __restrict__ bias, _Float16* __restrict__ C,
                 size_t a_estride,
                 const float* __restrict__ Wo, float* __restrict__ f, int e0)
{
    __shared__ _Float16 lt[4][64 * 72];   // per-wave epilogue repack tile

    const int tid  = threadIdx.x;
    const int lane = tid & 63;
    const int w    = tid >> 6;      // wave 0..3
    const int wm   = w & 1;
    const int wn   = w >> 1;

    // --- XCD-aware windowed remap (gridDim = {8, 64, g}) ---
    // flat%8 = XCD (matches HW round-robin). Within an XCD's expert-shard:
    // window = 4 m-tiles; decode s = [window][nb(3b)][mbi(2b)] so all 8
    // n-blocks of a 1MB A-window run before the next window.
    const int g    = gridDim.z;
    const int flat = blockIdx.x + (blockIdx.y << 3) + (blockIdx.z << 9);
    const int xcd  = flat & 7;
    int s = flat >> 3;
    int le, mb_base;
    if (g <= 8) {
        const int p = 8 / g;            // XCDs per expert
        le = xcd / p;
        mb_base = (xcd % p) * (64 / p);
    } else {                            // g == 16
        le = (xcd << 1) | (s >> 9);
        s &= 511;
        mb_base = 0;
    }
    const int nb = (s >> 2) & 7;
    const int mb = mb_base + (s >> 5) * 4 + (s & 3);
    const int m0 = mb * 128;
    const int n0 = nb * 128;

    const _Float16* Ae = A   + (size_t)le * a_estride;
    const _Float16* Be = Bt  + (size_t)le * (1024ull * 1024ull);
    const float*    be = bias + (size_t)le * 1024ull;
    _Float16*       Ce = C   + (size_t)le * (8192ull * 1024ull);

    const int mtb = (m0 >> 4) + wm * 4;   // wave's first m-tile
    const int ntb = (n0 >> 4) + wn * 4;   // wave's first n-tile

    // uniform SGPR bases (advance 512 halves per k-chunk) + u32 lane offsets
    const _Float16* bA = Ae + (size_t)mtb * 32 * 512;
    const _Float16* bB = Be + (size_t)ntb * 32 * 512;
    uint32_t offA[4], offB[4];
#pragma unroll
    for (int i = 0; i < 4; ++i) offA[i] = (uint32_t)(i * 32 * 512 + lane * 8);
#pragma unroll
    for (int j = 0; j < 4; ++j) offB[j] = (uint32_t)(j * 32 * 512 + lane * 8);

    floatx4 acc[4][4];
#pragma unroll
    for (int i = 0; i < 4; ++i)
#pragma unroll
        for (int j = 0; j < 4; ++j) { floatx4 z = {0.f, 0.f, 0.f, 0.f}; acc[i][j] = z; }

    half8 a0[4], b0[4], a1[4], b1[4];
#pragma unroll
    for (int i = 0; i < 4; ++i) a0[i] = *(const half8*)(bA + offA[i]);
#pragma unroll
    for (int j = 0; j < 4; ++j) b0[j] = *(const half8*)(bB + offB[j]);
    bA += 512; bB += 512;

    for (int t = 0; t < 15; ++t) {
#pragma unroll
        for (int i = 0; i < 4; ++i) a1[i] = *(const half8*)(bA + offA[i]);
#pragma unroll
        for (int j = 0; j < 4; ++j) b1[j] = *(const half8*)(bB + offB[j]);
        bA += 512; bB += 512;
#pragma unroll
        for (int i = 0; i < 4; ++i)
#pragma unroll
            for (int j = 0; j < 4; ++j)
                acc[i][j] = __builtin_amdgcn_mfma_f32_16x16x32_f16(a0[i], b0[j], acc[i][j], 0, 0, 0);
#pragma unroll
        for (int i = 0; i < 4; ++i) a0[i] = *(const half8*)(bA + offA[i]);
#pragma unroll
        for (int j = 0; j < 4; ++j) b0[j] = *(const half8*)(bB + offB[j]);
        bA += 512; bB += 512;
#pragma unroll
        for (int i = 0; i < 4; ++i)
#pragma unroll
            for (int j = 0; j < 4; ++j)
                acc[i][j] = __builtin_amdgcn_mfma_f32_16x16x32_f16(a1[i], b1[j], acc[i][j], 0, 0, 0);
    }
#pragma unroll
    for (int i = 0; i < 4; ++i) a1[i] = *(const half8*)(bA + offA[i]);
#pragma unroll
    for (int j = 0; j < 4; ++j) b1[j] = *(const half8*)(bB + offB[j]);
#pragma unroll
    for (int i = 0; i < 4; ++i)
#pragma unroll
        for (int j = 0; j < 4; ++j)
            acc[i][j] = __builtin_amdgcn_mfma_f32_16x16x32_f16(a0[i], b0[j], acc[i][j], 0, 0, 0);
#pragma unroll
    for (int i = 0; i < 4; ++i)
#pragma unroll
        for (int j = 0; j < 4; ++j)
            acc[i][j] = __builtin_amdgcn_mfma_f32_16x16x32_f16(a1[i], b1[j], acc[i][j], 0, 0, 0);

    // ----- epilogue; C/D layout: col=lane&15, row=(lane>>4)*4+r -----
    const int q   = lane >> 4;
    const int l15 = lane & 15;
    float bj[4];
#pragma unroll
    for (int j = 0; j < 4; ++j) bj[j] = be[n0 + wn * 64 + j * 16 + l15];

    if (ACT == 2) {
        // f[m, e0+le] += sum_n (acc + b2[n]) * Wo[e0+le, n]
        const float* we = Wo + (size_t)(e0 + le) * 1024;
        float wj[4];
#pragma unroll
        for (int j = 0; j < 4; ++j) wj[j] = we[n0 + wn * 64 + j * 16 + l15];
#pragma unroll
        for (int i = 0; i < 4; ++i) {
            const int mbase = m0 + wm * 64 + i * 16 + q * 4;
#pragma unroll
            for (int r = 0; r < 4; ++r) {
                float sacc = 0.f;
#pragma unroll
                for (int j = 0; j < 4; ++j) sacc += (acc[i][j][r] + bj[j]) * wj[j];
#pragma unroll
                for (int m = 1; m < 16; m <<= 1) sacc += __shfl_xor(sacc, m, 64);
                if (l15 == 0) atomicAdd(&f[(size_t)(mbase + r) * 16 + (e0 + le)], sacc);
            }
        }
    } else {
        // per-wave LDS repack (no cross-wave access -> no barrier needed)
        _Float16* T = lt[w];
#pragma unroll
        for (int i = 0; i < 4; ++i)
#pragma unroll
            for (int r = 0; r < 4; ++r) {
                const int row = i * 16 + q * 4 + r;
#pragma unroll
                for (int j = 0; j < 4; ++j) {
                    float v = acc[i][j][r] + bj[j];
                    if (ACT == 0) v = 1.0f / (1.0f + __expf(-v));
                    else          v = fmaxf(v, 0.0f);
                    T[row * 72 + j * 16 + l15] = (_Float16)v;
                }
            }
        // read in frag order + vectorized store
        const int kcg0 = ((n0 + wn * 64) >> 5);
#pragma unroll
        for (int i = 0; i < 4; ++i) {
            const int mt = mtb + i;
#pragma unroll
            for (int kci = 0; kci < 2; ++kci) {
                half8 v = *(const half8*)(T + (i * 16 + l15) * 72 + kci * 32 + q * 8);
                *(half8*)(Ce + ((size_t)mt * 32 + kcg0 + kci) * 512 + lane * 8) = v;
            }
        }
    }
}

// --------------------------------------- cast x to fp16 frag layout ---------
__global__ __launch_bounds__(256)
void castx_kernel(const float* __restrict__ x, _Float16* __restrict__ xb)
{
    __shared__ _Float16 tile[64 * 72];   // [m-local][k-local]
    const int k0 = blockIdx.x * 64;
    const int m0 = blockIdx.y * 64;
    const int tid = threadIdx.x;
    const int col4 = (tid & 15) * 4;
    const int rb   = tid >> 4;           // 0..15
#pragma unroll
    for (int p = 0; p < 4; ++p) {
        const int row = rb + p * 16;
        float4 a = *(const float4*)(x + (size_t)(m0 + row) * 1024 + k0 + col4);
        _Float16* d = tile + row * 72 + col4;
        d[0] = (_Float16)a.x; d[1] = (_Float16)a.y; d[2] = (_Float16)a.z; d[3] = (_Float16)a.w;
    }
    __syncthreads();
    const int lane = tid & 63, w = tid >> 6;
    const int l15 = lane & 15, q = lane >> 4;
#pragma unroll
    for (int ff = 0; ff < 2; ++ff) {
        const int fidx = w * 2 + ff;
        const int mi = fidx >> 1, kci = fidx & 1;
        half8 v = *(const half8*)(tile + (mi * 16 + l15) * 72 + kci * 32 + q * 8);
        const size_t mt = (m0 >> 4) + mi, kc = (k0 >> 5) + kci;
        *(half8*)(xb + (mt * 32 + kc) * 512 + lane * 8) = v;
    }
}

// ------------------- W1/W2 [d][h] fp32 -> frag-major fp16 (n=h, k=d) --------
__global__ __launch_bounds__(256)
void wtr_kernel(const float* __restrict__ W1, const float* __restrict__ W2,
                _Float16* __restrict__ W1F, _Float16* __restrict__ W2F)
{
    __shared__ _Float16 tile[64 * 73];   // [k-local][n-local], pad 73
    const int z = blockIdx.z;
    const float* src = (z < 16) ? (W1 + (size_t)z * 1048576ull) : (W2 + (size_t)(z - 16) * 1048576ull);
    _Float16*    dst = (z < 16) ? (W1F + (size_t)z * 1048576ull) : (W2F + (size_t)(z - 16) * 1048576ull);
    const int n0 = blockIdx.x * 64;
    const int k0 = blockIdx.y * 64;
    const int tid = threadIdx.x;
    const int col = tid & 63;
    const int rb  = tid >> 6;            // 0..3
#pragma unroll
    for (int p = 0; p < 16; ++p) {
        const int row = rb * 16 + p;
        tile[row * 73 + col] = (_Float16)src[(size_t)(k0 + row) * 1024 + n0 + col];
    }
    __syncthreads();
    const int lane = tid & 63, w = tid >> 6;
    const int l15 = lane & 15, q = lane >> 4;
#pragma unroll
    for (int ff = 0; ff < 2; ++ff) {
        const int fidx = w * 2 + ff;
        const int nti = fidx >> 1, kci = fidx & 1;
        half8 v;
#pragma unroll
        for (int jj = 0; jj < 8; ++jj)
            v[jj] = tile[(kci * 32 + q * 8 + jj) * 73 + nti * 16 + l15];
        const size_t nt = (n0 >> 4) + nti, kc = (k0 >> 5) + kci;
        *(half8*)(dst + (nt * 32 + kc) * 512 + lane * 8) = v;
    }
}

// ---------------------------------------------------- zero f ----------------
__global__ __launch_bounds__(256)
void zerof_kernel(float* __restrict__ f)
{
    const size_t i = ((size_t)blockIdx.x * 256 + threadIdx.x) * 4;
    float4 z = {0.f, 0.f, 0.f, 0.f};
    *(float4*)(f + i) = z;
}

// ------------------ gates (fp32, full precision) + softmax + combine --------
__global__ __launch_bounds__(256)
void final_kernel(const float* __restrict__ x,
                  const float* __restrict__ Wg1, const float* __restrict__ bg1,
                  const float* __restrict__ Wg2, const float* __restrict__ bg2,
                  const float* __restrict__ f, const float* __restrict__ bo,
                  float* __restrict__ out)
{
    const int lane = threadIdx.x & 63;
    const int w    = threadIdx.x >> 6;
    const int b    = blockIdx.x * 4 + w;
    const float* xr = x + (size_t)b * 1024;
    float gp1[16], gp2[16];
#pragma unroll
    for (int e = 0; e < 16; ++e) { gp1[e] = 0.f; gp2[e] = 0.f; }
    for (int t = 0; t < 16; ++t) {
        const int d = t * 64 + lane;
        const float xv = xr[d];
        const float* w1r = Wg1 + (size_t)d * 16;
        const float* w2r = Wg2 + (size_t)d * 16;
#pragma unroll
        for (int e = 0; e < 16; ++e) { gp1[e] += xv * w1r[e]; gp2[e] += xv * w2r[e]; }
    }
#pragma unroll
    for (int e = 0; e < 16; ++e) {
#pragma unroll
        for (int m = 1; m < 64; m <<= 1) {
            gp1[e] += __shfl_xor(gp1[e], m, 64);
            gp2[e] += __shfl_xor(gp2[e], m, 64);
        }
    }
    float a1[16], a2[16], m1 = -1e30f, m2 = -1e30f;
#pragma unroll
    for (int e = 0; e < 16; ++e) {
        a1[e] = gp1[e] + bg1[e]; m1 = fmaxf(m1, a1[e]);
        a2[e] = gp2[e] + bg2[e]; m2 = fmaxf(m2, a2[e]);
    }
    float s1 = 0.f, s2 = 0.f;
#pragma unroll
    for (int e = 0; e < 16; ++e) {
        a1[e] = __expf(a1[e] - m1); s1 += a1[e];
        a2[e] = __expf(a2[e] - m2); s2 += a2[e];
    }
    float o1 = 0.f, o2 = 0.f;
    const float* fb = f + (size_t)b * 16;
#pragma unroll
    for (int e = 0; e < 16; ++e) {
        const float fe = fb[e] + bo[e];
        o1 += a1[e] * fe; o2 += a2[e] * fe;
    }
    if (lane == 0) { out[b] = o1 / s1; out[8192 + b] = o2 / s2; }
}

// ----------------------------------------------------------------------------
extern "C" void kernel_launch(void* const* d_in, const int* in_sizes, int n_in,
                              void* d_out, int out_size, void* d_ws, size_t ws_size,
                              hipStream_t stream)
{
    const float* x   = (const float*)d_in[0];
    const float* W1  = (const float*)d_in[1];
    const float* b1  = (const float*)d_in[2];
    const float* W2  = (const float*)d_in[3];
    const float* b2  = (const float*)d_in[4];
    const float* Wo  = (const float*)d_in[5];
    const float* bo  = (const float*)d_in[6];
    const float* Wg1 = (const float*)d_in[7];
    const float* bg1 = (const float*)d_in[8];
    const float* Wg2 = (const float*)d_in[9];
    const float* bg2 = (const float*)d_in[10];
    float* out = (float*)d_out;

    char* ws = (char*)d_ws;
    _Float16* xb  = (_Float16*)(ws);                         // 16 MB (frag)
    _Float16* W1F = (_Float16*)(ws + 16777216ull);           // 32 MB (frag)
    _Float16* W2F = (_Float16*)(ws + 50331648ull);           // 32 MB (frag)
    float*    f   = (float*)   (ws + 83886080ull);           // 0.5 MB
    char* hbase = ws + 84410368ull;

    int g = 1;
    const int cands[4] = {16, 8, 4, 2};
    for (int ci = 0; ci < 4; ++ci) {
        const size_t need = 84410368ull + 2ull * cands[ci] * 16777216ull;
        if (need <= ws_size) { g = cands[ci]; break; }
    }
    _Float16* h0 = (_Float16*)hbase;
    _Float16* h1 = (_Float16*)(hbase + (size_t)g * 16777216ull);

    castx_kernel<<<dim3(16, 128), 256, 0, stream>>>(x, xb);
    wtr_kernel<<<dim3(16, 16, 32), 256, 0, stream>>>(W1, W2, W1F, W2F);
    zerof_kernel<<<128, 256, 0, stream>>>(f);

    for (int e0 = 0; e0 < 16; e0 += g) {
        gemm_kernel<0><<<dim3(8, 64, g), 256, 0, stream>>>(
            xb, W1F + (size_t)e0 * 1048576ull, b1 + (size_t)e0 * 1024, h0, 0,
            nullptr, nullptr, 0);
        gemm_kernel<1><<<dim3(8, 64, g), 256, 0, stream>>>(
            h0, W2F + (size_t)e0 * 1048576ull, b2 + (size_t)e0 * 1024, h1, 8192ull * 1024ull,
            nullptr, nullptr, 0);
        gemm_kernel<2><<<dim3(8, 64, g), 256, 0, stream>>>(
            h1, W2F + (size_t)e0 * 1048576ull, b2 + (size_t)e0 * 1024, h0, 8192ull * 1024ull,
            Wo, f, e0);
    }
    final_kernel<<<2048, 256, 0, stream>>>(x, Wg1, bg1, Wg2, bg2, f, bo, out);
}